// Round 4
// baseline (1698.173 us; speedup 1.0000x reference)
//
#include <hip/hip_runtime.h>
#include <cstdint>
#include <cstddef>

// Better_Transformer: B=16384, IN=4096, P=8, D=512
// out = swish2( blockmm( swish1( blockmm(x*g1+nb1, W1)+b1 )*g3+nb3, W2)+b2 ) + x
//
// R4: fused per-partition kernel + intra-block m-tile pipeline.
//  - R1/R3 post-mortem: ~1 resident block/CU, lockstep phase chain
//    stage(HBM) -> K1 -> epi1 -> K2 -> epi2(HBM) with nothing to overlap the
//    HBM-latency phases. R2 showed more lockstep waves don't help.
//  - Fix: each block processes T=4 m-tiles. x(t+1) is loaded into REGISTERS
//    (8 x float4/thread) at the top of phase1(t) -- ~900cy HBM latency hides
//    under both K-loops -- and converted into LDS after phase2(t)'s last read.
//    Residual+store of tile t overlap the conversion. Only the block prologue
//    (1 of 4 tiles) keeps an exposed stage.
//  - Dropped the R3 explicit weight prefetch (measured null) to free regs for
//    the xf prefetch: 96 + 32 = 128 = the (1024,4) cap.
//  - Weights direct from global ([n][k] layout), L2-pinned per XCD via
//    grid.x = p. No barriers inside K-loops. o1 never touches HBM.

#define B_ROWS 16384
#define IN_SZ  4096
#define P_PART 8
#define D_DIM  512
#define M_BLK  64
#define T_TILES 4

typedef unsigned short ushort_t;
typedef __attribute__((ext_vector_type(8))) short short8;   // 8 x bf16 bits (4 VGPRs)
typedef __attribute__((ext_vector_type(4))) float f32x4;    // MFMA accumulator

__device__ inline unsigned short f2bf(float f) {
  union { float f; unsigned int u; } c; c.f = f;
  unsigned int u = c.u;
  return (unsigned short)((u + 0x7fffu + ((u >> 16) & 1u)) >> 16);  // RNE
}

// swizzled ushort index into a [M_BLK][D_DIM] bf16 LDS tile.
__device__ inline int swz(int m, int c) { return m * D_DIM + (c ^ ((m & 7) << 3)); }

// ---------------------------------------------------------------- weight prep
// Wt[p][n][k] = W[p][k][n], fp32 -> bf16. grid (8 ktile, 8 ntile, 16), block 256
__global__ __launch_bounds__(256) void wconv_kernel(const float* __restrict__ w1,
                                                    const float* __restrict__ w2,
                                                    ushort_t* __restrict__ wt1,
                                                    ushort_t* __restrict__ wt2) {
  __shared__ float tile[64][68];  // +4 pad
  const int p = blockIdx.z & 7;
  const float*  src = (blockIdx.z < 8) ? w1 : w2;
  ushort_t*     dst = (blockIdx.z < 8) ? wt1 : wt2;
  const int k0 = blockIdx.x * 64;
  const int n0 = blockIdx.y * 64;
  const int t = threadIdx.x;

  const float* base = src + ((size_t)p * D_DIM + k0) * D_DIM + n0;
#pragma unroll
  for (int i = 0; i < 4; ++i) {
    int f = t + i * 256;          // 0..1023
    int kr = f >> 4;
    int c4 = f & 15;
    float4 v = *(const float4*)(base + (size_t)kr * D_DIM + c4 * 4);
    *(float4*)(&tile[kr][c4 * 4]) = v;
  }
  __syncthreads();
  ushort_t* obase = dst + ((size_t)p * D_DIM + n0) * D_DIM + k0;
#pragma unroll
  for (int i = 0; i < 4; ++i) {
    int f = t + i * 256;
    int nr = f >> 4;
    int kc = (f & 15) * 4;
    unsigned int lo = f2bf(tile[kc + 0][nr]) | ((unsigned int)f2bf(tile[kc + 1][nr]) << 16);
    unsigned int hi = f2bf(tile[kc + 2][nr]) | ((unsigned int)f2bf(tile[kc + 3][nr]) << 16);
    uint2 pk; pk.x = lo; pk.y = hi;
    *(uint2*)(obase + (size_t)nr * D_DIM + kc) = pk;
  }
}

// ---------------------------------------------------------------- fused kernel
// block: p = blockIdx.x, tiles m0 = (blockIdx.y*T + tt)*64. 1024 thr = 16
// waves; wave wid owns n-slice [wid*32, wid*32+32) in both phases. 64KB LDS.
__global__ __launch_bounds__(1024, 4) void fused_kernel(
    const float* __restrict__ x,
    const ushort_t* __restrict__ wt1, const ushort_t* __restrict__ wt2,
    const float* __restrict__ bias1, const float* __restrict__ gamma1,
    const float* __restrict__ beta1,
    const float* __restrict__ bias2, const float* __restrict__ gamma3,
    const float* __restrict__ beta3,
    const float* __restrict__ gain1, const float* __restrict__ nbias1,
    const float* __restrict__ gain3, const float* __restrict__ nbias3,
    float* __restrict__ out) {
  __shared__ __align__(16) ushort_t Xs[M_BLK * D_DIM];  // 64KB; x tile, then o1 tile

  const int t = threadIdx.x;
  const int lane = t & 63, wid = t >> 6;   // 16 waves
  const int l15 = lane & 15, quad = lane >> 4;
  const int p  = blockIdx.x;
  const int by = blockIdx.y;

  const float g1 = gain1[0], nb1 = nbias1[0];
  const float g3 = gain3[0], nb3 = nbias3[0];

  const ushort_t* w1b = wt1 + (size_t)p * D_DIM * D_DIM + (size_t)(wid * 32 + l15) * D_DIM;
  const ushort_t* w2b = wt2 + (size_t)p * D_DIM * D_DIM + (size_t)(wid * 32 + l15) * D_DIM;

  // ---- prologue: load + convert tile 0
  float4 xf[8];
  {
    const float* xb = x + (size_t)(by * T_TILES) * M_BLK * IN_SZ + (size_t)p * D_DIM;
#pragma unroll
    for (int i = 0; i < 8; ++i) {
      int g = t + i * 1024;
      xf[i] = *(const float4*)(xb + (size_t)(g >> 7) * IN_SZ + (g & 127) * 4);
    }
  }
#pragma unroll
  for (int i = 0; i < 8; ++i) {
    int g = t + i * 1024;
    int m = g >> 7, c = (g & 127) * 4;
    uint2 pk;
    pk.x = f2bf(xf[i].x * g1 + nb1) | ((unsigned int)f2bf(xf[i].y * g1 + nb1) << 16);
    pk.y = f2bf(xf[i].z * g1 + nb1) | ((unsigned int)f2bf(xf[i].w * g1 + nb1) << 16);
    *(uint2*)(&Xs[swz(m, c)]) = pk;
  }

#pragma unroll 1
  for (int tt = 0; tt < T_TILES; ++tt) {
    const int m0 = (by * T_TILES + tt) * M_BLK;
    __syncthreads();                       // A: Xs = bf16 x(tt) ready

    // ---- issue x(tt+1) loads into registers (hidden under both K-loops)
    if (tt + 1 < T_TILES) {
      const float* xb = x + (size_t)(m0 + M_BLK) * IN_SZ + (size_t)p * D_DIM;
#pragma unroll
      for (int i = 0; i < 8; ++i) {
        int g = t + i * 1024;
        xf[i] = *(const float4*)(xb + (size_t)(g >> 7) * IN_SZ + (g & 127) * 4);
      }
    }

    // ---- phase 1: acc[i][j] = W1-slice x X   (swapped operands)
    // a: W1t[p][n = wid*32 + i*16 + l15][kof..+7]  (global, L2-resident)
    // b: Xs [m = j*16 + l15][kof..+7]
    f32x4 acc[2][4];
#pragma unroll
    for (int i = 0; i < 2; ++i)
#pragma unroll
      for (int j = 0; j < 4; ++j) acc[i][j] = (f32x4)(0.0f);

#pragma unroll
    for (int s = 0; s < 16; ++s) {
      const int kof = s * 32 + quad * 8;
      short8 a0 = *(const short8*)(w1b + kof);
      short8 a1 = *(const short8*)(w1b + (size_t)16 * D_DIM + kof);
      short8 b[4];
#pragma unroll
      for (int j = 0; j < 4; ++j)
        b[j] = *(const short8*)(&Xs[swz(j * 16 + l15, kof)]);
#pragma unroll
      for (int j = 0; j < 4; ++j) {
        acc[0][j] = __builtin_amdgcn_mfma_f32_16x16x32_bf16(a0, b[j], acc[0][j], 0, 0, 0);
        acc[1][j] = __builtin_amdgcn_mfma_f32_16x16x32_bf16(a1, b[j], acc[1][j], 0, 0, 0);
      }
    }

    __syncthreads();   // B: all Xs reads done before overwrite

    // ---- epilogue 1: o1 = swish1(acc + b1)*g3 + nb3 -> bf16 -> Xs (as [m][n])
#pragma unroll
    for (int i = 0; i < 2; ++i) {
      const int n = wid * 32 + i * 16 + quad * 4;
      const int col = p * D_DIM + n;
      const float4 bv = *(const float4*)(bias1 + col);
      const float4 ga = *(const float4*)(gamma1 + col);
      const float4 be = *(const float4*)(beta1 + col);
#pragma unroll
      for (int j = 0; j < 4; ++j) {
        const int m = j * 16 + l15;
        float o[4];
#pragma unroll
        for (int r = 0; r < 4; ++r) {
          float v = acc[i][j][r] + ((const float*)&bv)[r];
          float g = ((const float*)&ga)[r];
          float sg = 1.0f / (1.0f + __expf(-((const float*)&be)[r] * v));
          o[r] = ((g + sg * (1.0f - g)) * v) * g3 + nb3;
        }
        uint2 pk;
        pk.x = f2bf(o[0]) | ((unsigned int)f2bf(o[1]) << 16);
        pk.y = f2bf(o[2]) | ((unsigned int)f2bf(o[3]) << 16);
        *(uint2*)(&Xs[swz(m, n)]) = pk;
      }
    }
    __syncthreads();   // C: o1 ready

    // ---- phase 2: acc2[i][j] = o1 x W2-slice  (normal orientation)
    // a: Xs [m = i*16 + l15][kof..+7]
    // b: W2t[p][n = wid*32 + j*16 + l15][kof..+7]
    f32x4 acc2[4][2];
#pragma unroll
    for (int i = 0; i < 4; ++i)
#pragma unroll
      for (int j = 0; j < 2; ++j) acc2[i][j] = (f32x4)(0.0f);

#pragma unroll
    for (int s = 0; s < 16; ++s) {
      const int kof = s * 32 + quad * 8;
      short8 b0 = *(const short8*)(w2b + kof);
      short8 b1 = *(const short8*)(w2b + (size_t)16 * D_DIM + kof);
      short8 a[4];
#pragma unroll
      for (int i = 0; i < 4; ++i)
        a[i] = *(const short8*)(&Xs[swz(i * 16 + l15, kof)]);
#pragma unroll
      for (int i = 0; i < 4; ++i) {
        acc2[i][0] = __builtin_amdgcn_mfma_f32_16x16x32_bf16(a[i], b0, acc2[i][0], 0, 0, 0);
        acc2[i][1] = __builtin_amdgcn_mfma_f32_16x16x32_bf16(a[i], b1, acc2[i][1], 0, 0, 0);
      }
    }

    __syncthreads();   // D: all o1 reads done; Xs free for x(tt+1)

    // ---- epilogue 2: out = swish2(acc2 + b2) + x  (overlaps the convert below)
    const int colg0 = p * D_DIM + wid * 32;
#pragma unroll
    for (int j = 0; j < 2; ++j) {
      const int col = colg0 + j * 16 + l15;
      const float bv = bias2[col], ga = gamma3[col], be = beta3[col];
#pragma unroll
      for (int i = 0; i < 4; ++i) {
        const int r0 = m0 + i * 16 + quad * 4;
#pragma unroll
        for (int r = 0; r < 4; ++r) {
          float v = acc2[i][j][r] + bv;
          float sg = 1.0f / (1.0f + __expf(-be * v));
          float o = (ga + sg * (1.0f - ga)) * v;
          const size_t idx = (size_t)(r0 + r) * IN_SZ + col;
          out[idx] = o + x[idx];
        }
      }
    }

    // ---- convert x(tt+1) regs -> Xs (loads issued a whole 2 K-loops ago)
    if (tt + 1 < T_TILES) {
#pragma unroll
      for (int i = 0; i < 8; ++i) {
        int g = t + i * 1024;
        int m = g >> 7, c = (g & 127) * 4;
        uint2 pk;
        pk.x = f2bf(xf[i].x * g1 + nb1) | ((unsigned int)f2bf(xf[i].y * g1 + nb1) << 16);
        pk.y = f2bf(xf[i].z * g1 + nb1) | ((unsigned int)f2bf(xf[i].w * g1 + nb1) << 16);
        *(uint2*)(&Xs[swz(m, c)]) = pk;
      }
    }
  }
}

// ---------------------------------------------------------------- launch
extern "C" void kernel_launch(void* const* d_in, const int* in_sizes, int n_in,
                              void* d_out, int out_size, void* d_ws, size_t ws_size,
                              hipStream_t stream) {
  const float* x      = (const float*)d_in[0];
  const float* w1     = (const float*)d_in[1];
  const float* b1     = (const float*)d_in[2];
  const float* w2     = (const float*)d_in[3];
  const float* b2     = (const float*)d_in[4];
  const float* gamma1 = (const float*)d_in[5];
  const float* beta1  = (const float*)d_in[6];
  const float* gamma3 = (const float*)d_in[7];
  const float* beta3  = (const float*)d_in[8];
  const float* gain1  = (const float*)d_in[9];
  const float* nbias1 = (const float*)d_in[10];
  const float* gain3  = (const float*)d_in[11];
  const float* nbias3 = (const float*)d_in[12];
  float* out = (float*)d_out;

  // ws layout: Wt1 bf16 (4MB) | Wt2 bf16 (4MB)
  ushort_t* wt1 = (ushort_t*)d_ws;
  ushort_t* wt2 = wt1 + (size_t)P_PART * D_DIM * D_DIM;

  wconv_kernel<<<dim3(8, 8, 16), 256, 0, stream>>>(w1, w2, wt1, wt2);
  // grid.x = p so linear block id % 8 == p: pins partition p's weights to XCD p's L2
  fused_kernel<<<dim3(P_PART, B_ROWS / (M_BLK * T_TILES)), 1024, 0, stream>>>(
      x, wt1, wt2, b1, gamma1, beta1, b2, gamma3, beta3,
      gain1, nbias1, gain3, nbias3, out);
}

// Round 5
// 770.041 us; speedup vs baseline: 2.2053x; 2.2053x over previous
//
#include <hip/hip_runtime.h>
#include <cstdint>
#include <cstddef>

// Better_Transformer: B=16384, IN=4096, P=8, D=512
// out = swish2( blockmm( swish1( blockmm(x*g1+nb1, W1)+b1 )*g3+nb3, W2)+b2 ) + x
//
// R5: fused per-partition kernel; weight loads converted to global_load_lds
// with per-wave PRIVATE double-buffered LDS panels + counted vmcnt.
//  - R1-R4 synthesis: wall time tracks weight-load count; ~1 load in flight
//    per wave (register-destination loads are sunk just-in-time by the
//    scheduler under the 128-reg cap; R3 reg-prefetch null, R4 spill blowup).
//  - gld_lds needs NO result VGPR and its issue point is pinned -> deep MLP.
//    Each wave stages its 64n x 32k W panel (4KB) into its own LDS dbuf slot,
//    computing panel s while s+1 is in flight: s_waitcnt vmcnt(4), never 0
//    mid-loop. No cross-wave barriers in K-loops (private buffers).
//  - Panel layout: call i stages rows i*16+l15, k=quad*8..+7 -> slot lane*16;
//    frag read = base + i*1024 + lane*16: linear, conflict-free, static offs.
//  - W2 panels 0/1 issued before epilogue-1 (latency hides under swish VALU).
//  - LDS 64KB Xs + 64KB panels = 128KB -> 1 block/CU, 8 waves, bounds (512,2).
//  - setprio(1) around MFMA cluster (waves at different depths -> T5 regime).

#define B_ROWS 16384
#define IN_SZ  4096
#define P_PART 8
#define D_DIM  512
#define M_BLK  64

typedef unsigned short ushort_t;
typedef __attribute__((ext_vector_type(8))) short short8;   // 8 x bf16 bits (4 VGPRs)
typedef __attribute__((ext_vector_type(4))) float f32x4;    // MFMA accumulator

__device__ inline unsigned short f2bf(float f) {
  union { float f; unsigned int u; } c; c.f = f;
  unsigned int u = c.u;
  return (unsigned short)((u + 0x7fffu + ((u >> 16) & 1u)) >> 16);  // RNE
}

__device__ inline void gld_to_lds16(const void* g, void* l) {
  // 16B per lane, LDS dest = wave-uniform base + lane*16
  __builtin_amdgcn_global_load_lds((const __attribute__((address_space(1))) void*)g,
                                   (__attribute__((address_space(3))) void*)l,
                                   16, 0, 0);
}

// swizzled ushort index into a [M_BLK][D_DIM] bf16 LDS tile.
__device__ inline int swz(int m, int c) { return m * D_DIM + (c ^ ((m & 7) << 3)); }

// ---------------------------------------------------------------- weight prep
// Wt[p][n][k] = W[p][k][n], fp32 -> bf16. grid (8 ktile, 8 ntile, 16), block 256
__global__ __launch_bounds__(256) void wconv_kernel(const float* __restrict__ w1,
                                                    const float* __restrict__ w2,
                                                    ushort_t* __restrict__ wt1,
                                                    ushort_t* __restrict__ wt2) {
  __shared__ float tile[64][68];  // +4 pad
  const int p = blockIdx.z & 7;
  const float*  src = (blockIdx.z < 8) ? w1 : w2;
  ushort_t*     dst = (blockIdx.z < 8) ? wt1 : wt2;
  const int k0 = blockIdx.x * 64;
  const int n0 = blockIdx.y * 64;
  const int t = threadIdx.x;

  const float* base = src + ((size_t)p * D_DIM + k0) * D_DIM + n0;
#pragma unroll
  for (int i = 0; i < 4; ++i) {
    int f = t + i * 256;          // 0..1023
    int kr = f >> 4;
    int c4 = f & 15;
    float4 v = *(const float4*)(base + (size_t)kr * D_DIM + c4 * 4);
    *(float4*)(&tile[kr][c4 * 4]) = v;
  }
  __syncthreads();
  ushort_t* obase = dst + ((size_t)p * D_DIM + n0) * D_DIM + k0;
#pragma unroll
  for (int i = 0; i < 4; ++i) {
    int f = t + i * 256;
    int nr = f >> 4;
    int kc = (f & 15) * 4;
    unsigned int lo = f2bf(tile[kc + 0][nr]) | ((unsigned int)f2bf(tile[kc + 1][nr]) << 16);
    unsigned int hi = f2bf(tile[kc + 2][nr]) | ((unsigned int)f2bf(tile[kc + 3][nr]) << 16);
    uint2 pk; pk.x = lo; pk.y = hi;
    *(uint2*)(obase + (size_t)nr * D_DIM + kc) = pk;
  }
}

// ---------------------------------------------------------------- fused kernel
// block: p = blockIdx.x, m0 = blockIdx.y*64. 512 thr = 8 waves; wave wn owns
// the 64-col n-slice [wn*64, wn*64+64) in both phases. 128KB LDS, 1 block/CU.
__global__ __launch_bounds__(512, 2) void fused_kernel(
    const float* __restrict__ x,
    const ushort_t* __restrict__ wt1, const ushort_t* __restrict__ wt2,
    const float* __restrict__ bias1, const float* __restrict__ gamma1,
    const float* __restrict__ beta1,
    const float* __restrict__ bias2, const float* __restrict__ gamma3,
    const float* __restrict__ beta3,
    const float* __restrict__ gain1, const float* __restrict__ nbias1,
    const float* __restrict__ gain3, const float* __restrict__ nbias3,
    float* __restrict__ out) {
  __shared__ __align__(16) ushort_t Xs[M_BLK * D_DIM];  // 64KB; x tile, then o1 tile
  __shared__ __align__(16) ushort_t Ws[8 * 4096];       // 64KB; per-wave 2x4KB W panels

  const int t = threadIdx.x;
  const int lane = t & 63, wn = t >> 6;
  const int l15 = lane & 15, quad = lane >> 4;
  const int p  = blockIdx.x;
  const int m0 = blockIdx.y * M_BLK;

  const float g1 = gain1[0], nb1 = nbias1[0];
  const float g3 = gain3[0], nb3 = nbias3[0];

  // this lane's weight row base (row = wn*64 + i*16 + l15, +i*16 rows per call)
  const ushort_t* w1r = wt1 + (size_t)p * D_DIM * D_DIM + (size_t)(wn * 64 + l15) * D_DIM;
  const ushort_t* w2r = wt2 + (size_t)p * D_DIM * D_DIM + (size_t)(wn * 64 + l15) * D_DIM;
  ushort_t* pb = Ws + wn * 4096;   // wave-private: 2 panels x 2048 ushorts (4KB)

  // stage panel s of weight matrix (rows wn*64..+63, k = s*32..+31) into buf
#define STAGE_W(wr, s, buf) do {                                               \
    const ushort_t* g_ = (wr) + (s) * 32 + quad * 8;                           \
    gld_to_lds16(g_,                         pb + (buf) * 2048);               \
    gld_to_lds16(g_ + (size_t)16 * D_DIM,    pb + (buf) * 2048 + 512);         \
    gld_to_lds16(g_ + (size_t)32 * D_DIM,    pb + (buf) * 2048 + 1024);        \
    gld_to_lds16(g_ + (size_t)48 * D_DIM,    pb + (buf) * 2048 + 1536);        \
  } while (0)

  // ---- issue W1 panels 0,1 first (latency hides under the x stage)
  STAGE_W(w1r, 0, 0);
  STAGE_W(w1r, 1, 1);

  // ---- stage x[m0:m0+64][p*512:+512] -> bf16(x*g1+nb1), swizzled
  {
    const float* xb = x + (size_t)m0 * IN_SZ + (size_t)p * D_DIM;
#pragma unroll
    for (int i = 0; i < 16; ++i) {
      int g = t + i * 512;             // 0..8191 float4-groups
      int m = g >> 7;                  // 128 groups per row
      int c = (g & 127) * 4;
      float4 v = *(const float4*)(xb + (size_t)m * IN_SZ + c);
      uint2 pk;
      pk.x = f2bf(v.x * g1 + nb1) | ((unsigned int)f2bf(v.y * g1 + nb1) << 16);
      pk.y = f2bf(v.z * g1 + nb1) | ((unsigned int)f2bf(v.w * g1 + nb1) << 16);
      *(uint2*)(&Xs[swz(m, c)]) = pk;
    }
  }
  __syncthreads();                     // A: Xs ready (drains vmcnt -> panels 0,1 landed)

  // ---- phase 1: acc[i][j] = W1-slice x X   (swapped operands)
  // a[i]: panel slot i*512 + lane*8 (= W1 row wn*64+i*16+l15, k quad*8..+7)
  // b[j]: Xs [m = j*16 + l15][kof..+7]
  // D: (quad*4+r) -> n-within-frag, l15 -> m-within-frag
  f32x4 acc[4][4];
#pragma unroll
  for (int i = 0; i < 4; ++i)
#pragma unroll
    for (int j = 0; j < 4; ++j) acc[i][j] = (f32x4)(0.0f);

#pragma unroll
  for (int s = 0; s < 16; ++s) {
    if (s < 15) asm volatile("s_waitcnt vmcnt(4)" ::: "memory");
    else        asm volatile("s_waitcnt vmcnt(0)" ::: "memory");
    const ushort_t* pc = pb + (s & 1) * 2048;
    short8 a[4], b[4];
#pragma unroll
    for (int i = 0; i < 4; ++i)
      a[i] = *(const short8*)(pc + i * 512 + lane * 8);
    const int kof = s * 32 + quad * 8;
#pragma unroll
    for (int j = 0; j < 4; ++j)
      b[j] = *(const short8*)(&Xs[swz(j * 16 + l15, kof)]);
    asm volatile("s_waitcnt lgkmcnt(0)" ::: "memory");
    __builtin_amdgcn_sched_barrier(0);
    if (s + 2 < 16) STAGE_W(w1r, s + 2, s & 1);   // refill the buffer just read
    __builtin_amdgcn_s_setprio(1);
#pragma unroll
    for (int i = 0; i < 4; ++i)
#pragma unroll
      for (int j = 0; j < 4; ++j)
        acc[i][j] = __builtin_amdgcn_mfma_f32_16x16x32_bf16(a[i], b[j], acc[i][j], 0, 0, 0);
    __builtin_amdgcn_s_setprio(0);
  }

  __syncthreads();   // B: all Xs reads done before overwrite

  // ---- issue W2 panels 0,1 (latency hides under epilogue-1 VALU)
  STAGE_W(w2r, 0, 0);
  STAGE_W(w2r, 1, 1);

  // ---- epilogue 1: o1 = swish1(acc + b1)*g3 + nb3 -> bf16 -> Xs (as [m][n])
#pragma unroll
  for (int i = 0; i < 4; ++i) {
    const int n = wn * 64 + i * 16 + quad * 4;
    const int col = p * D_DIM + n;
    const float4 bv = *(const float4*)(bias1 + col);
    const float4 ga = *(const float4*)(gamma1 + col);
    const float4 be = *(const float4*)(beta1 + col);
#pragma unroll
    for (int j = 0; j < 4; ++j) {
      const int m = j * 16 + l15;
      float o[4];
#pragma unroll
      for (int r = 0; r < 4; ++r) {
        float v = acc[i][j][r] + ((const float*)&bv)[r];
        float g = ((const float*)&ga)[r];
        float sg = 1.0f / (1.0f + __expf(-((const float*)&be)[r] * v));
        o[r] = ((g + sg * (1.0f - g)) * v) * g3 + nb3;
      }
      uint2 pk;
      pk.x = f2bf(o[0]) | ((unsigned int)f2bf(o[1]) << 16);
      pk.y = f2bf(o[2]) | ((unsigned int)f2bf(o[3]) << 16);
      *(uint2*)(&Xs[swz(m, n)]) = pk;
    }
  }
  __syncthreads();   // C: o1 ready (drains vmcnt -> W2 panels 0,1 landed)

  // ---- phase 2: acc2[i][j] = o1 x W2-slice  (normal orientation)
  // a[i]: Xs [m = i*16 + l15][kof..+7]
  // b[j]: panel slot j*512 + lane*8
  f32x4 acc2[4][4];
#pragma unroll
  for (int i = 0; i < 4; ++i)
#pragma unroll
    for (int j = 0; j < 4; ++j) acc2[i][j] = (f32x4)(0.0f);

#pragma unroll
  for (int s = 0; s < 16; ++s) {
    if (s < 15) asm volatile("s_waitcnt vmcnt(4)" ::: "memory");
    else        asm volatile("s_waitcnt vmcnt(0)" ::: "memory");
    const ushort_t* pc = pb + (s & 1) * 2048;
    short8 a[4], b[4];
    const int kof = s * 32 + quad * 8;
#pragma unroll
    for (int i = 0; i < 4; ++i)
      a[i] = *(const short8*)(&Xs[swz(i * 16 + l15, kof)]);
#pragma unroll
    for (int j = 0; j < 4; ++j)
      b[j] = *(const short8*)(pc + j * 512 + lane * 8);
    asm volatile("s_waitcnt lgkmcnt(0)" ::: "memory");
    __builtin_amdgcn_sched_barrier(0);
    if (s + 2 < 16) STAGE_W(w2r, s + 2, s & 1);
    __builtin_amdgcn_s_setprio(1);
#pragma unroll
    for (int i = 0; i < 4; ++i)
#pragma unroll
      for (int j = 0; j < 4; ++j)
        acc2[i][j] = __builtin_amdgcn_mfma_f32_16x16x32_bf16(a[i], b[j], acc2[i][j], 0, 0, 0);
    __builtin_amdgcn_s_setprio(0);
  }

  // ---- epilogue 2: out = swish2(acc2 + b2) + x   (fp32, coalesced 64B runs)
  const int colg0 = p * D_DIM + wn * 64;
#pragma unroll
  for (int j = 0; j < 4; ++j) {
    const int col = colg0 + j * 16 + l15;
    const float bv = bias2[col], ga = gamma3[col], be = beta3[col];
#pragma unroll
    for (int i = 0; i < 4; ++i) {
      const int r0 = m0 + i * 16 + quad * 4;
#pragma unroll
      for (int r = 0; r < 4; ++r) {
        float v = acc2[i][j][r] + bv;
        float sg = 1.0f / (1.0f + __expf(-be * v));
        float o = (ga + sg * (1.0f - ga)) * v;
        const size_t idx = (size_t)(r0 + r) * IN_SZ + col;
        out[idx] = o + x[idx];
      }
    }
  }
#undef STAGE_W
}

// ---------------------------------------------------------------- launch
extern "C" void kernel_launch(void* const* d_in, const int* in_sizes, int n_in,
                              void* d_out, int out_size, void* d_ws, size_t ws_size,
                              hipStream_t stream) {
  const float* x      = (const float*)d_in[0];
  const float* w1     = (const float*)d_in[1];
  const float* b1     = (const float*)d_in[2];
  const float* w2     = (const float*)d_in[3];
  const float* b2     = (const float*)d_in[4];
  const float* gamma1 = (const float*)d_in[5];
  const float* beta1  = (const float*)d_in[6];
  const float* gamma3 = (const float*)d_in[7];
  const float* beta3  = (const float*)d_in[8];
  const float* gain1  = (const float*)d_in[9];
  const float* nbias1 = (const float*)d_in[10];
  const float* gain3  = (const float*)d_in[11];
  const float* nbias3 = (const float*)d_in[12];
  float* out = (float*)d_out;

  // ws layout: Wt1 bf16 (4MB) | Wt2 bf16 (4MB)
  ushort_t* wt1 = (ushort_t*)d_ws;
  ushort_t* wt2 = wt1 + (size_t)P_PART * D_DIM * D_DIM;

  wconv_kernel<<<dim3(8, 8, 16), 256, 0, stream>>>(w1, w2, wt1, wt2);
  // grid.x = p so linear block id % 8 == p: pins partition p's weights to XCD p's L2
  fused_kernel<<<dim3(P_PART, B_ROWS / M_BLK), 512, 0, stream>>>(
      x, wt1, wt2, b1, gamma1, beta1, b2, gamma3, beta3,
      gain1, nbias1, gain3, nbias3, out);
}